// Round 9
// baseline (93.781 us; speedup 1.0000x reference)
//
#include <hip/hip_runtime.h>
#include <hip/hip_bf16.h>

#define N_ROWS 8192
#define DIM 256
#define NANCH 64
#define NVIEW 128
#define NPART 8     // column partitions (8 anchors = 1024 cols each)

typedef __attribute__((ext_vector_type(8))) short bf16x8;
typedef __attribute__((ext_vector_type(16))) float f32x16;
typedef __attribute__((ext_vector_type(4))) float float4v;
typedef __attribute__((ext_vector_type(4))) unsigned short ushort4v;

__device__ __forceinline__ unsigned short f2bf(float x) {
  union { float f; unsigned int u; } c; c.f = x;
  unsigned int u = c.u;
  unsigned int r = (u + 0x7fffu + ((u >> 16) & 1u)) >> 16;
  return (unsigned short)r;
}

__device__ __forceinline__ float bf2f(unsigned short b) {
  union { unsigned int u; float f; } c; c.u = ((unsigned int)b) << 16;
  return c.f;
}

__device__ __forceinline__ void gload_lds16(const void* g, void* l) {
  __builtin_amdgcn_global_load_lds(
      (const __attribute__((address_space(1))) unsigned int*)g,
      (__attribute__((address_space(3))) unsigned int*)l, 16, 0, 0);
}

// fp32 -> bf16 with 1/sqrt(T) prescale, fused with per-row squared-norm
// (= the Gram diagonal = the row max of the logits). One wave per row.
__global__ void cast_diag_kernel(const float4v* __restrict__ in,
                                 ushort4v* __restrict__ out,
                                 float* __restrict__ diag) {
  const int w = threadIdx.x >> 6;
  const int l = threadIdx.x & 63;
  const int row = blockIdx.x * 4 + w;
  const float s = 3.16227766016838f; // 1/sqrt(0.1)
  float4v v = in[row * 64 + l];
  ushort4v o;
  o.x = f2bf(v.x * s);
  o.y = f2bf(v.y * s);
  o.z = f2bf(v.z * s);
  o.w = f2bf(v.w * s);
  out[row * 64 + l] = o;
  float c0 = bf2f(o.x), c1 = bf2f(o.y), c2 = bf2f(o.z), c3 = bf2f(o.w);
  float ss = c0 * c0 + c1 * c1 + c2 * c2 + c3 * c3;
#pragma unroll
  for (int st = 1; st < 64; st <<= 1) ss += __shfl_xor(ss, st);
  if (l == 0) diag[row] = ss;
}

// -------- Kernel 2: full fused pass over (128 rows x 1024 cols) per block.
// grid = 64 row-anchors x 8 parts (bx = rb*8 + part: same-part blocks land on
// one XCD -> its 512 KB B-panel stays L2-resident). 256 threads = 4 waves
// (2 row-groups x 2 col-groups), ~220 VGPR, 66 KB LDS -> 2 blocks/CU: the
// second block's waves fill this block's barrier/vmcnt bubbles (round-8 was
// a single 8-wave block in lockstep -> MfmaUtil capped at 29%).
// Streams 16 half-anchor B tiles (64 cols x K=256, 32 KB, k-major
// conflict-free LDS) through a 2-slot ring; counted vmcnt(8), never 0
// mid-loop. Row max is KNOWN (= diag).
// NEGATIVE anchors -> ns += exp(v - diag)   [underflow-skipped]
// POSITIVE anchors -> sd += (v - diag)      [always; diagonal masked]
//                     ep += exp(v - diag)   [underflow-skipped, diag masked]
// so the positives pass (old pcl_pos kernel) is gone entirely.
__global__ __launch_bounds__(256, 2) void pcl_negsum(
    const unsigned short* __restrict__ Xb, const int* __restrict__ labels,
    const float* __restrict__ diag, float* __restrict__ ns_partial,
    float* __restrict__ sd_partial, float* __restrict__ ep_partial) {
  const int bx = blockIdx.x;
  const int part = bx & 7;            // 0..7 -> col anchors part*8 .. +7
  const int rb = bx >> 3;             // row anchor (128 rows, uniform label)
  const int abase = part * 8;
  const int tid = threadIdx.x;        // 0..255
  const int wid = tid >> 6;           // 0..3
  const int lane = tid & 63;
  const int l31 = lane & 31;
  const int khalf = lane >> 5;
  const int rg = wid >> 1;            // row group (64 rows)
  const int cg = wid & 1;             // col group (32 cols)
  const int R0 = rb * 128;

  __shared__ __align__(16) unsigned short ring[2 * 64 * DIM];  // 2 x 32 KB
  __shared__ float sdiag[128];
  __shared__ float nsacc[128];
  __shared__ float sdacc[128];
  __shared__ float epacc[128];
  __shared__ int slab[NANCH];

  if (tid < NANCH) slab[tid] = labels[tid];
  if (tid < 128) {
    sdiag[tid] = diag[R0 + tid];
    nsacc[tid] = 0.f;
    sdacc[tid] = 0.f;
    epacc[tid] = 0.f;
  }
  __syncthreads();
  const int myLab = slab[rb];

  // A fragments: lane holds row R0 + rg*64 + ri*32 + l31, k = ks*16+khalf*8.
  // Pins force materialization (drains the A-load vmcnt before staging
  // starts, keeping the counted-vmcnt bookkeeping exact).
  bf16x8 afrag[2][16];
#pragma unroll
  for (int ri = 0; ri < 2; ++ri) {
#pragma unroll
    for (int ks = 0; ks < 16; ++ks) {
      const unsigned short* p =
          Xb + (size_t)(R0 + rg * 64 + ri * 32 + l31) * DIM + ks * 16 + khalf * 8;
      afrag[ri][ks] = *(const bf16x8*)p;
    }
  }
#pragma unroll
  for (int ri = 0; ri < 2; ++ri)
#pragma unroll
    for (int ks = 0; ks < 16; ++ks) asm volatile("" : "+v"(afrag[ri][ks]));

  // Wave-uniform skip threshold: min diag over this wave's 64 rows - 40.
  float thr;
  {
    float d = sdiag[rg * 64 + lane];
#pragma unroll
    for (int st = 1; st < 64; st <<= 1) d = fminf(d, __shfl_xor(d, st));
    thr = d - 40.f;
  }

  char* const L0 = (char*)&ring[0];

  // Stage half-tile H (anchor abase+(H>>1), col-half H&1) into slot H&1.
  // Thread covers chunks g = i*256+tid (i=0..7): k-octet = i*4+wid, col=lane.
#define STAGE(H)                                                                \
  do {                                                                          \
    const unsigned short* _s =                                                  \
        Xb + (size_t)((abase + ((H) >> 1)) * NVIEW + ((H) & 1) * 64 + lane) *   \
                 DIM + wid * 8;                                                 \
    char* _d = L0 + ((H) & 1) * 32768 + wid * 1024;                             \
    _Pragma("unroll") for (int i = 0; i < 8; ++i)                               \
        gload_lds16(_s + i * 32, _d + i * 4096);                                \
  } while (0)

  STAGE(0);

#define BODY(S, VNSTR)                                                          \
  do {                                                                          \
    if ((S) + 1 < 16) STAGE((S) + 1);                                           \
    asm volatile("s_waitcnt vmcnt(" VNSTR ")");                                 \
    __builtin_amdgcn_sched_barrier(0);                                          \
    __builtin_amdgcn_s_barrier();                                               \
    __builtin_amdgcn_sched_barrier(0);                                          \
    const char* _sb = L0 + ((S) & 1) * 32768 + khalf * 1024 + cg * 512 + l31 * 16; \
    f32x16 a0A = {}, a0B = {}, a1A = {}, a1B = {};                              \
    __builtin_amdgcn_s_setprio(1);                                              \
    _Pragma("unroll") for (int ks = 0; ks < 8; ++ks) {                          \
      bf16x8 b0 = *(const bf16x8*)(_sb + ks * 2048);                            \
      bf16x8 b1 = *(const bf16x8*)(_sb + (ks + 8) * 2048);                      \
      a0A = __builtin_amdgcn_mfma_f32_32x32x16_bf16(afrag[0][ks], b0, a0A, 0, 0, 0); \
      a1A = __builtin_amdgcn_mfma_f32_32x32x16_bf16(afrag[1][ks], b0, a1A, 0, 0, 0); \
      a0B = __builtin_amdgcn_mfma_f32_32x32x16_bf16(afrag[0][ks + 8], b1, a0B, 0, 0, 0); \
      a1B = __builtin_amdgcn_mfma_f32_32x32x16_bf16(afrag[1][ks + 8], b1, a1B, 0, 0, 0); \
    }                                                                           \
    __builtin_amdgcn_s_setprio(0);                                              \
    const bool is_pos = (slab[abase + ((S) >> 1)] == myLab);                    \
    f32x16 c0 = a0A + a0B;                                                      \
    f32x16 c1 = a1A + a1B;                                                      \
    float vmax = fmaxf(c0[0], c1[0]);                                           \
    _Pragma("unroll") for (int r = 1; r < 16; ++r)                              \
        vmax = fmaxf(vmax, fmaxf(c0[r], c1[r]));                                \
    const bool anyhot = __any(vmax > thr);                                      \
    if (__builtin_expect(is_pos, 0)) {                                          \
      if (!anyhot) {                                                            \
        _Pragma("unroll") for (int t2 = 0; t2 < 2; ++t2) {                      \
          _Pragma("unroll") for (int r = 0; r < 16; ++r) {                      \
            const int rloc = (r & 3) + 8 * (r >> 2) + 4 * khalf;                \
            const int row = rg * 64 + t2 * 32 + rloc;                           \
            float d = (t2 ? c1[r] : c0[r]) - sdiag[row];                        \
            _Pragma("unroll") for (int st = 1; st < 32; st <<= 1)               \
                d += __shfl_xor(d, st);                                         \
            if (l31 == 0) atomicAdd(&sdacc[row], d);                            \
          }                                                                     \
        }                                                                       \
      } else {                                                                  \
        const bool dt = (abase + ((S) >> 1)) == rb;                             \
        _Pragma("unroll") for (int t2 = 0; t2 < 2; ++t2) {                      \
          _Pragma("unroll") for (int r = 0; r < 16; ++r) {                      \
            const int rloc = (r & 3) + 8 * (r >> 2) + 4 * khalf;                \
            const int row = rg * 64 + t2 * 32 + rloc;                           \
            const int cl = ((S) & 1) * 64 + cg * 32 + l31;                      \
            const bool isdiag = dt && (row == cl);                              \
            float v = (t2 ? c1[r] : c0[r]);                                     \
            float d = v - sdiag[row];                                           \
            float sd_e = isdiag ? 0.f : d;                                      \
            float e = (!isdiag && d > -40.f) ? __expf(d) : 0.f;                 \
            _Pragma("unroll") for (int st = 1; st < 32; st <<= 1) {             \
              sd_e += __shfl_xor(sd_e, st);                                     \
              e += __shfl_xor(e, st);                                           \
            }                                                                   \
            if (l31 == 0) {                                                     \
              atomicAdd(&sdacc[row], sd_e);                                     \
              if (e != 0.f) atomicAdd(&epacc[row], e);                          \
            }                                                                   \
          }                                                                     \
        }                                                                       \
      }                                                                         \
    } else if (__builtin_expect(anyhot, 0)) {                                   \
      _Pragma("unroll") for (int t2 = 0; t2 < 2; ++t2) {                        \
        _Pragma("unroll") for (int r = 0; r < 16; ++r) {                        \
          const int rloc = (r & 3) + 8 * (r >> 2) + 4 * khalf;                  \
          const int row = rg * 64 + t2 * 32 + rloc;                             \
          float d = (t2 ? c1[r] : c0[r]) - sdiag[row];                          \
          float e = (d > -40.f) ? __expf(d) : 0.f;                              \
          _Pragma("unroll") for (int st = 1; st < 32; st <<= 1)                 \
              e += __shfl_xor(e, st);                                           \
          if (l31 == 0) atomicAdd(&nsacc[row], e);                              \
        }                                                                       \
      }                                                                         \
    }                                                                           \
    __builtin_amdgcn_s_barrier();                                               \
  } while (0)

  BODY(0, "8");  BODY(1, "8");  BODY(2, "8");  BODY(3, "8");
  BODY(4, "8");  BODY(5, "8");  BODY(6, "8");  BODY(7, "8");
  BODY(8, "8");  BODY(9, "8");  BODY(10, "8"); BODY(11, "8");
  BODY(12, "8"); BODY(13, "8"); BODY(14, "8"); BODY(15, "0");

#undef BODY
#undef STAGE

  __syncthreads();
  if (tid < 128) {
    ns_partial[part * N_ROWS + R0 + tid] = nsacc[tid];
    sd_partial[part * N_ROWS + R0 + tid] = sdacc[tid];
    ep_partial[part * N_ROWS + R0 + tid] = epacc[tid];
  }
}

// -------- Kernel 3: per-row combine. 32 blocks x 256 threads, 1 row/thread.
// mean_log_prob_pos = (SD - npos*log(NS+eps) - EP/(NS+eps)) / npos
// (first-order-exact; EP==0 for non-degenerate data so it's the exact
// fast-path formula of the old pos kernel).
__global__ void pcl_combine(const int* __restrict__ labels,
                            const float* __restrict__ ns_partial,
                            const float* __restrict__ sd_partial,
                            const float* __restrict__ ep_partial,
                            float* __restrict__ partials) {
  const int tid = threadIdx.x;
  const int row = blockIdx.x * 256 + tid;
  __shared__ int slab[NANCH];
  __shared__ float sred[256];
  if (tid < NANCH) slab[tid] = labels[tid];
  __syncthreads();

  const int lab = slab[row >> 7];
  int cnt = 0;
#pragma unroll
  for (int b = 0; b < NANCH; ++b) cnt += (slab[b] == lab) ? 1 : 0;

  float NS = 0.f, SD = 0.f, EP = 0.f;
#pragma unroll
  for (int p = 0; p < NPART; ++p) {
    NS += ns_partial[p * N_ROWS + row];
    SD += sd_partial[p * N_ROWS + row];
    EP += ep_partial[p * N_ROWS + row];
  }
  const float npos = (float)(cnt * NVIEW - 1);
  const float nse = NS + 1e-10f;
  const float mlpp = (SD - npos * __logf(nse) - EP / nse) / npos;
  sred[tid] = mlpp;
  __syncthreads();
  for (int st = 128; st > 0; st >>= 1) {
    if (tid < st) sred[tid] += sred[tid + st];
    __syncthreads();
  }
  if (tid == 0) partials[blockIdx.x] = sred[0];
}

__global__ void final_reduce(const float* __restrict__ partials, float* __restrict__ out) {
  __shared__ float s[32];
  int t = threadIdx.x;
  if (t < 32) s[t] = partials[t];
  __syncthreads();
  if (t == 0) {
    float sum = 0.f;
    for (int r = 0; r < 32; ++r) sum += s[r];
    out[0] = -(0.1f / 0.07f) * sum / (float)N_ROWS;
  }
}

extern "C" void kernel_launch(void* const* d_in, const int* in_sizes, int n_in,
                              void* d_out, int out_size, void* d_ws, size_t ws_size,
                              hipStream_t stream) {
  const float* feats = (const float*)d_in[0];
  const int* labels = (const int*)d_in[1];
  float* out = (float*)d_out;

  char* base = (char*)d_ws;
  unsigned short* Xb = (unsigned short*)d_ws;                      // 4 MB
  size_t off = (size_t)N_ROWS * DIM * 2;
  float* diag = (float*)(base + off);       off += N_ROWS * 4;     // 32 KB
  float* ns_partial = (float*)(base + off); off += NPART * N_ROWS * 4;
  float* sd_partial = (float*)(base + off); off += NPART * N_ROWS * 4;
  float* ep_partial = (float*)(base + off); off += NPART * N_ROWS * 4;
  float* partials = (float*)(base + off);

  cast_diag_kernel<<<N_ROWS / 4, 256, 0, stream>>>((const float4v*)feats,
                                                   (ushort4v*)Xb, diag);
  pcl_negsum<<<NANCH * NPART, 256, 0, stream>>>(Xb, labels, diag, ns_partial,
                                                sd_partial, ep_partial);
  pcl_combine<<<N_ROWS / 256, 256, 0, stream>>>(labels, ns_partial, sd_partial,
                                                ep_partial, partials);
  final_reduce<<<1, 64, 0, stream>>>(partials, out);
}